// Round 1
// baseline (149.448 us; speedup 1.0000x reference)
//
#include <hip/hip_runtime.h>
#include <stdint.h>

// Problem constants
static constexpr int B_ROWS = 8192;
static constexpr int C_COLS = 1024;
static constexpr uint32_t HALF_N = 4194304u;  // B*C/2 = 4096 rows * 1024

__device__ __forceinline__ uint32_t rotl32(uint32_t x, int d) {
  return (x << d) | (x >> (32 - d));
}

// JAX Threefry-2x32 with key (0, 42), 20 rounds.
__device__ __forceinline__ void threefry2x32_k42(uint32_t& x0, uint32_t& x1) {
  const uint32_t ks0 = 0u;
  const uint32_t ks1 = 42u;
  const uint32_t ks2 = 0u ^ 42u ^ 0x1BD11BDAu;
  x0 += ks0; x1 += ks1;
#define TF_R(r) { x0 += x1; x1 = rotl32(x1, (r)); x1 ^= x0; }
  TF_R(13) TF_R(15) TF_R(26) TF_R(6)
  x0 += ks1; x1 += ks2 + 1u;
  TF_R(17) TF_R(29) TF_R(16) TF_R(24)
  x0 += ks2; x1 += ks0 + 2u;
  TF_R(13) TF_R(15) TF_R(26) TF_R(6)
  x0 += ks0; x1 += ks1 + 3u;
  TF_R(17) TF_R(29) TF_R(16) TF_R(24)
  x0 += ks1; x1 += ks2 + 4u;
  TF_R(13) TF_R(15) TF_R(26) TF_R(6)
  x0 += ks2; x1 += ks0 + 5u;
#undef TF_R
}

__global__ void init_accum_kernel(double* acc) { *acc = 0.0; }

__global__ void finalize_kernel(const double* acc, float* out) {
  out[0] = (float)(-(*acc) / ((double)B_ROWS * (double)C_COLS));
}

// One block handles rows b and b+4096 (they share threefry counter pairs).
// 256 threads, 4 columns each (float4/int4 vector loads).
__global__ __launch_bounds__(256) void attr_loss_main(
    const float* __restrict__ scores, const int* __restrict__ attrs,
    double* __restrict__ accum) {
  __shared__ int hist[256];
  __shared__ int wsum[4];
  __shared__ int sh_digit, sh_excl, sh_nzero;
  __shared__ float wred[4];

  const int b = blockIdx.x;       // 0..4095
  const int t = threadIdx.x;      // 0..255
  const int lane = t & 63;
  const int wid = t >> 6;
  const int c0 = t * 4;

  float sc[2][4];
  uint32_t key[2][4];
  int zm[2];  // bit j set iff attr==0 at column c0+j

  {
    const float4 s0 = *reinterpret_cast<const float4*>(scores + (size_t)b * C_COLS + c0);
    const float4 s1 = *reinterpret_cast<const float4*>(scores + (size_t)(b + 4096) * C_COLS + c0);
    sc[0][0] = s0.x; sc[0][1] = s0.y; sc[0][2] = s0.z; sc[0][3] = s0.w;
    sc[1][0] = s1.x; sc[1][1] = s1.y; sc[1][2] = s1.z; sc[1][3] = s1.w;
    const int4 a0 = *reinterpret_cast<const int4*>(attrs + (size_t)b * C_COLS + c0);
    const int4 a1 = *reinterpret_cast<const int4*>(attrs + (size_t)(b + 4096) * C_COLS + c0);
    zm[0] = (a0.x == 0 ? 1 : 0) | (a0.y == 0 ? 2 : 0) | (a0.z == 0 ? 4 : 0) | (a0.w == 0 ? 8 : 0);
    zm[1] = (a1.x == 0 ? 1 : 0) | (a1.y == 0 ? 2 : 0) | (a1.z == 0 ? 4 : 0) | (a1.w == 0 ? 8 : 0);
  }

  // Threefry bits for both paired rows; build 32-bit sort keys:
  // top 23 bits = uniform mantissa, low 9 bits = col>>1 (stable-ish tiebreak).
#pragma unroll
  for (int j = 0; j < 4; ++j) {
    uint32_t x0 = (uint32_t)b * (uint32_t)C_COLS + (uint32_t)(c0 + j);
    uint32_t x1 = x0 + HALF_N;
    threefry2x32_k42(x0, x1);
    const uint32_t cb = (uint32_t)(c0 + j) >> 1;
    key[0][j] = (x0 & 0xFFFFFE00u) | cb;
    key[1][j] = (x1 & 0xFFFFFE00u) | cb;
  }

  float rowsum[2] = {0.f, 0.f};

#pragma unroll
  for (int r = 0; r < 2; ++r) {
    // ---- radix select: key value at rank (k-1) among zero-attr positions ----
    uint32_t prefix = 0;
    int target = 0;
    int n_zero = 0;

#pragma unroll
    for (int p = 0; p < 4; ++p) {
      const int shift = 24 - 8 * p;
      hist[t] = 0;
      __syncthreads();
#pragma unroll
      for (int j = 0; j < 4; ++j) {
        if (zm[r] & (1 << j)) {
          const uint32_t kk = key[r][j];
          bool sel;
          if (p == 0) sel = true;
          else        sel = ((kk >> (shift + 8)) == prefix);
          if (sel) atomicAdd(&hist[(kk >> shift) & 255u], 1);
        }
      }
      __syncthreads();
      const int cbin = hist[t];
      // wave-inclusive scan then cross-wave offsets
      int v = cbin;
#pragma unroll
      for (int d = 1; d < 64; d <<= 1) {
        const int o = __shfl_up(v, d, 64);
        if (lane >= d) v += o;
      }
      if (lane == 63) wsum[wid] = v;
      __syncthreads();
      int base = 0;
#pragma unroll
      for (int w = 0; w < 3; ++w)
        if (w < wid) base += wsum[w];
      const int excl = base + v - cbin;

      if (p == 0) {
        if (t == 255) sh_nzero = excl + cbin;
        __syncthreads();
        n_zero = sh_nzero;
        // k = round-half-even(0.95f * n_zero) in f32, matches jnp.round
        target = (int)rintf(0.95f * (float)n_zero) - 1;
      }
      if (n_zero > 0) {
        if (excl <= target && target < excl + cbin) {
          sh_digit = t;
          sh_excl = excl;
        }
      }
      __syncthreads();
      if (n_zero > 0) {
        prefix = (prefix << 8) | (uint32_t)sh_digit;
        target -= sh_excl;
      }
    }
    const uint32_t T = prefix;  // key at sorted rank k-1 (valid iff n_zero>0)

    // ---- masked loss sum for this row ----
    float s_local = 0.f;
#pragma unroll
    for (int j = 0; j < 4; ++j) {
      const float s = sc[r][j];
      const float commonv = log1pf(expf(-fabsf(s)));
      if (zm[r] & (1 << j)) {
        // attr==0: kept iff key strictly above threshold (rank >= k)
        if (key[r][j] > T) s_local += fminf(-s, 0.f) - commonv;
      } else {
        // attr==1: always kept, log_sigmoid(s)
        s_local += fminf(s, 0.f) - commonv;
      }
    }
    // block reduce
    float rv = s_local;
#pragma unroll
    for (int d = 32; d >= 1; d >>= 1) rv += __shfl_down(rv, d, 64);
    if (lane == 0) wred[wid] = rv;
    __syncthreads();
    if (t == 0) rowsum[r] = wred[0] + wred[1] + wred[2] + wred[3];
    __syncthreads();
  }

  if (t == 0) {
    atomicAdd(accum, (double)rowsum[0] + (double)rowsum[1]);
  }
}

extern "C" void kernel_launch(void* const* d_in, const int* in_sizes, int n_in,
                              void* d_out, int out_size, void* d_ws, size_t ws_size,
                              hipStream_t stream) {
  const float* scores = (const float*)d_in[0];
  const int* attrs = (const int*)d_in[1];
  float* out = (float*)d_out;
  double* accum = (double*)d_ws;  // 8 bytes of scratch

  init_accum_kernel<<<1, 1, 0, stream>>>(accum);
  attr_loss_main<<<B_ROWS / 2, 256, 0, stream>>>(scores, attrs, accum);
  finalize_kernel<<<1, 1, 0, stream>>>(accum, out);
}

// Round 2
// 118.176 us; speedup vs baseline: 1.2646x; 1.2646x over previous
//
#include <hip/hip_runtime.h>
#include <stdint.h>

// Problem constants
static constexpr int B_ROWS = 8192;
static constexpr int C_COLS = 1024;
static constexpr uint32_t HALF_N = 4194304u;  // B*C/2
static constexpr int NPAIR = B_ROWS / 2;      // 4096 row-pairs
static constexpr int MAIN_BLOCKS = NPAIR / 4; // 1024 blocks, 1 wave = 1 pair

__device__ __forceinline__ uint32_t rotl32(uint32_t x, int d) {
  return (x << d) | (x >> (32 - d));
}

// JAX Threefry-2x32 with key (0, 42), 20 rounds. (verified bit-exact in R0)
__device__ __forceinline__ void threefry2x32_k42(uint32_t& x0, uint32_t& x1) {
  const uint32_t ks0 = 0u;
  const uint32_t ks1 = 42u;
  const uint32_t ks2 = 0u ^ 42u ^ 0x1BD11BDAu;
  x0 += ks0; x1 += ks1;
#define TF_R(r) { x0 += x1; x1 = rotl32(x1, (r)); x1 ^= x0; }
  TF_R(13) TF_R(15) TF_R(26) TF_R(6)
  x0 += ks1; x1 += ks2 + 1u;
  TF_R(17) TF_R(29) TF_R(16) TF_R(24)
  x0 += ks2; x1 += ks0 + 2u;
  TF_R(13) TF_R(15) TF_R(26) TF_R(6)
  x0 += ks0; x1 += ks1 + 3u;
  TF_R(17) TF_R(29) TF_R(16) TF_R(24)
  x0 += ks1; x1 += ks2 + 4u;
  TF_R(13) TF_R(15) TF_R(26) TF_R(6)
  x0 += ks2; x1 += ks0 + 5u;
#undef TF_R
}

// One wave per row-pair (rows p and p+4096 share threefry counter pairs).
// Lane layout: lane holds cols {i*256 + lane*4 + j : i in 0..3, j in 0..3}
// -> perfectly coalesced float4/int4 loads.
__global__ __launch_bounds__(256) void attr_loss_main(
    const float* __restrict__ scores, const int* __restrict__ attrs,
    double* __restrict__ partials) {
  __shared__ int hist[4][256];
  __shared__ float wsumf[4];

  const int t = threadIdx.x;
  const int lane = t & 63;
  const int w = t >> 6;
  const int pair = blockIdx.x * 4 + w;  // 0..4095
  const int r0 = pair, r1 = pair + NPAIR;

  uint32_t key0[16], key1[16];
  uint32_t zm0 = 0, zm1 = 0;  // bit e set iff attr==0 at element e

#pragma unroll
  for (int i = 0; i < 4; ++i) {
    const int col = i * 256 + lane * 4;
    const int4 a0 = *reinterpret_cast<const int4*>(attrs + (size_t)r0 * C_COLS + col);
    const int4 a1 = *reinterpret_cast<const int4*>(attrs + (size_t)r1 * C_COLS + col);
    zm0 |= (a0.x == 0 ? 1u : 0u) << (i * 4 + 0);
    zm0 |= (a0.y == 0 ? 1u : 0u) << (i * 4 + 1);
    zm0 |= (a0.z == 0 ? 1u : 0u) << (i * 4 + 2);
    zm0 |= (a0.w == 0 ? 1u : 0u) << (i * 4 + 3);
    zm1 |= (a1.x == 0 ? 1u : 0u) << (i * 4 + 0);
    zm1 |= (a1.y == 0 ? 1u : 0u) << (i * 4 + 1);
    zm1 |= (a1.z == 0 ? 1u : 0u) << (i * 4 + 2);
    zm1 |= (a1.w == 0 ? 1u : 0u) << (i * 4 + 3);
  }

#pragma unroll
  for (int i = 0; i < 4; ++i) {
#pragma unroll
    for (int j = 0; j < 4; ++j) {
      const int col = i * 256 + lane * 4 + j;
      uint32_t x0 = (uint32_t)(r0 * C_COLS + col);
      uint32_t x1 = x0 + HALF_N;
      threefry2x32_k42(x0, x1);
      const uint32_t cb = (uint32_t)col >> 1;
      key0[i * 4 + j] = (x0 & 0xFFFFFE00u) | cb;
      key1[i * 4 + j] = (x1 & 0xFFFFFE00u) | cb;
    }
  }

  float lsum = 0.f;

#pragma unroll
  for (int r = 0; r < 2; ++r) {
    const uint32_t* key = r ? key1 : key0;
    const uint32_t zm = r ? zm1 : zm0;
    const float* srow = scores + (size_t)(r ? r1 : r0) * C_COLS;
    int* h = hist[w];

    // ---- wave-private 256-bin histogram of top byte (zero-attr keys) ----
    *reinterpret_cast<int4*>(h + lane * 4) = make_int4(0, 0, 0, 0);
    __syncthreads();
#pragma unroll
    for (int e = 0; e < 16; ++e) {
      if ((zm >> e) & 1u) atomicAdd(&h[key[e] >> 24], 1);
    }
    __syncthreads();
    const int4 hv = *reinterpret_cast<const int4*>(h + lane * 4);

    // ---- scan: find bucket containing rank k-1 ----
    const int s0 = hv.x, s1 = s0 + hv.y, s2 = s1 + hv.z, s3 = s2 + hv.w;
    int incl = s3;
#pragma unroll
    for (int d = 1; d < 64; d <<= 1) {
      const int o = __shfl_up(incl, d, 64);
      if (lane >= d) incl += o;
    }
    const int excl = incl - s3;
    const int n_zero = __shfl(incl, 63, 64);
    const int k = (int)rintf(0.95f * (float)n_zero);

    uint32_t T = 0u;
    if (k > 0) {
      const int target = k - 1;
      int myb = -1, myt = 0;
      const int ce0 = excl, ce1 = excl + s0, ce2 = excl + s1, ce3 = excl + s2;
      if (hv.x > 0 && ce0 <= target && target < ce0 + hv.x) { myb = lane * 4 + 0; myt = target - ce0; }
      if (hv.y > 0 && ce1 <= target && target < ce1 + hv.y) { myb = lane * 4 + 1; myt = target - ce1; }
      if (hv.z > 0 && ce2 <= target && target < ce2 + hv.z) { myb = lane * 4 + 2; myt = target - ce2; }
      if (hv.w > 0 && ce3 <= target && target < ce3 + hv.w) { myb = lane * 4 + 3; myt = target - ce3; }
      const unsigned long long bm = __ballot(myb >= 0);
      const int src = __ffsll((unsigned long long)bm) - 1;
      const uint32_t bucket = (uint32_t)__shfl(myb, src, 64);
      int tt = __shfl(myt, src, 64);

      // ---- exact k-th smallest within the bucket (expected ~2 candidates) ----
      uint32_t lowbar = 0u;
      while (true) {
        uint32_t mm = 0xFFFFFFFFu;
#pragma unroll
        for (int e = 0; e < 16; ++e) {
          const uint32_t kk = key[e];
          if (((zm >> e) & 1u) && (kk >> 24) == bucket && kk >= lowbar)
            mm = mm < kk ? mm : kk;
        }
#pragma unroll
        for (int d = 32; d >= 1; d >>= 1) {
          const uint32_t o = (uint32_t)__shfl_xor((int)mm, d, 64);
          mm = mm < o ? mm : o;
        }
        int c = 0;
#pragma unroll
        for (int e = 0; e < 16; ++e)
          c += (((zm >> e) & 1u) && key[e] == mm) ? 1 : 0;
#pragma unroll
        for (int d = 32; d >= 1; d >>= 1) c += __shfl_xor(c, d, 64);
        if (tt < c) { T = mm; break; }
        tt -= c;
        lowbar = mm + 1u;
      }
    }

    // ---- masked loss for this row ----
#pragma unroll
    for (int i = 0; i < 4; ++i) {
      const float4 sv = *reinterpret_cast<const float4*>(srow + i * 256 + lane * 4);
      const float ss[4] = {sv.x, sv.y, sv.z, sv.w};
#pragma unroll
      for (int j = 0; j < 4; ++j) {
        const int e = i * 4 + j;
        const float s = ss[j];
        // log1p(exp(-|s|)): arg in (1,2], fast log is absolutely accurate here
        const float cmn = __logf(1.f + __expf(-fabsf(s)));
        if ((zm >> e) & 1u) {
          if (k <= 0 || key[e] > T) lsum += fminf(-s, 0.f) - cmn;
        } else {
          lsum += fminf(s, 0.f) - cmn;
        }
      }
    }
    __syncthreads();  // hist WAR before next row's clear
  }

  // ---- block reduce -> per-block partial (no global atomics) ----
#pragma unroll
  for (int d = 32; d >= 1; d >>= 1) lsum += __shfl_xor(lsum, d, 64);
  if (lane == 0) wsumf[w] = lsum;
  __syncthreads();
  if (t == 0) {
    partials[blockIdx.x] =
        (double)wsumf[0] + (double)wsumf[1] + (double)wsumf[2] + (double)wsumf[3];
  }
}

__global__ __launch_bounds__(256) void finalize_kernel(
    const double* __restrict__ partials, float* __restrict__ out) {
  __shared__ double wred[4];
  const int t = threadIdx.x;
  const int lane = t & 63;
  const int w = t >> 6;
  double s = partials[t] + partials[t + 256] + partials[t + 512] + partials[t + 768];
#pragma unroll
  for (int d = 32; d >= 1; d >>= 1) s += __shfl_xor(s, d, 64);
  if (lane == 0) wred[w] = s;
  __syncthreads();
  if (t == 0) {
    const double tot = wred[0] + wred[1] + wred[2] + wred[3];
    out[0] = (float)(-tot / ((double)B_ROWS * (double)C_COLS));
  }
}

extern "C" void kernel_launch(void* const* d_in, const int* in_sizes, int n_in,
                              void* d_out, int out_size, void* d_ws, size_t ws_size,
                              hipStream_t stream) {
  const float* scores = (const float*)d_in[0];
  const int* attrs = (const int*)d_in[1];
  float* out = (float*)d_out;
  double* partials = (double*)d_ws;  // 1024 doubles = 8 KB scratch

  attr_loss_main<<<MAIN_BLOCKS, 256, 0, stream>>>(scores, attrs, partials);
  finalize_kernel<<<1, 256, 0, stream>>>(partials, out);
}